// Round 15
// baseline (270.753 us; speedup 1.0000x reference)
//
#include <hip/hip_runtime.h>
#include <stdint.h>

#define DEVINL __device__ __forceinline__

typedef float  f32x4  __attribute__((ext_vector_type(4)));
typedef float  f32x16 __attribute__((ext_vector_type(16)));
typedef short  s16x8  __attribute__((ext_vector_type(8)));
typedef unsigned short u16x4 __attribute__((ext_vector_type(4)));
typedef unsigned short u16x8 __attribute__((ext_vector_type(8)));

static constexpr int S = 2048, D = 1024, H = 16;
static constexpr size_t OUT0 = (size_t)2 * S * D;   // 4194304

DEVINL unsigned short f2bf(float f) {
  union { float f; unsigned u; } v; v.f = f;
  unsigned r = v.u + 0x7FFFu + ((v.u >> 16) & 1u);   // RNE
  return (unsigned short)(r >> 16);
}

DEVINL unsigned cvt_pk_bf16(float lo, float hi) {
  unsigned r;
  asm("v_cvt_pk_bf16_f32 %0, %1, %2" : "=v"(r) : "v"(lo), "v"(hi));
  return r;
}

DEVINL void perm32swap(unsigned& a, unsigned& b) {
#if __has_builtin(__builtin_amdgcn_permlane32_swap)
  auto r = __builtin_amdgcn_permlane32_swap(a, b, false, false);
  a = r[0]; b = r[1];
#else
  asm volatile("v_permlane32_swap_b32 %0, %1" : "+v"(a), "+v"(b));
#endif
}

DEVINL void gload_lds16(const void* g, void* l) {
  __builtin_amdgcn_global_load_lds(
      (const __attribute__((address_space(1))) unsigned int*)g,
      (__attribute__((address_space(3))) unsigned int*)l, 16, 0, 0);
}

// ---------------- fp32 -> bf16 convert, single launch for all 7 tensors ------
DEVINL void cvt_body(const float* __restrict__ src, unsigned short* __restrict__ dst, int i) {
  const f32x4* s4 = (const f32x4*)src;
  f32x4 a = s4[i * 2], b = s4[i * 2 + 1];
  u16x8 o;
  o[0] = f2bf(a[0]); o[1] = f2bf(a[1]); o[2] = f2bf(a[2]); o[3] = f2bf(a[3]);
  o[4] = f2bf(b[0]); o[5] = f2bf(b[1]); o[6] = f2bf(b[2]); o[7] = f2bf(b[3]);
  ((u16x8*)dst)[i] = o;
}

__global__ __launch_bounds__(256) void k_cvt_all(
    const float* __restrict__ Q, const float* __restrict__ K, const float* __restrict__ V,
    const float* __restrict__ Wq, const float* __restrict__ Wk,
    const float* __restrict__ Wv, const float* __restrict__ Wo,
    unsigned short* __restrict__ Xq, unsigned short* __restrict__ Xk,
    unsigned short* __restrict__ Xv,
    unsigned short* __restrict__ WQ, unsigned short* __restrict__ WK,
    unsigned short* __restrict__ WV, unsigned short* __restrict__ WO) {
  int i = blockIdx.x;
  const float* src; unsigned short* dst; int item;
  if (i < 6144) {
    int z = i >> 11;
    item = (i & 2047) * 256 + threadIdx.x;
    src = z == 0 ? Q : z == 1 ? K : V;
    dst = z == 0 ? Xq : z == 1 ? Xk : Xv;
  } else {
    int j = i - 6144, z = j >> 9;
    item = (j & 511) * 256 + threadIdx.x;
    src = z == 0 ? Wq : z == 1 ? Wk : z == 2 ? Wv : Wo;
    dst = z == 0 ? WQ : z == 1 ? WK : z == 2 ? WV : WO;
  }
  cvt_body(src, dst, item);
}

// ------- GEMM core: C[128,128] tile, BK=32, double-buffered (round-14) -------
template <int MODE>
DEVINL void gemm_tile(const unsigned short* __restrict__ A,
                      const unsigned short* __restrict__ Bw,
                      const float* __restrict__ bias, void* __restrict__ Cout,
                      int tileM, int tileN, float scl, char* smem) {
  const int tid = threadIdx.x;
  const int lane = tid & 63, wave = tid >> 6;
  const int wr = wave >> 1, wc = wave & 1;
  const int l15 = lane & 15, l16 = lane >> 4;
  f32x4 acc[4][4] = {};

#pragma unroll
  for (int p = 0; p < 2; ++p) {
    int c = tid + p * 256;
    int row = c >> 2, col = (c & 3) * 8;
    gload_lds16(A + (((size_t)(tileM + row)) << 10) + col, smem + c * 16);
    gload_lds16(Bw + (((size_t)(tileN + row)) << 10) + col, smem + 8192 + c * 16);
  }
  __syncthreads();

  int cur = 0;
  for (int k0 = 0; k0 < 1024; k0 += 32) {
    if (k0 + 32 < 1024) {
      int nxt = (cur ^ 1) * 16384;
#pragma unroll
      for (int p = 0; p < 2; ++p) {
        int c = tid + p * 256;
        int row = c >> 2, col = (c & 3) * 8;
        gload_lds16(A + (((size_t)(tileM + row)) << 10) + k0 + 32 + col, smem + nxt + c * 16);
        gload_lds16(Bw + (((size_t)(tileN + row)) << 10) + k0 + 32 + col, smem + nxt + 8192 + c * 16);
      }
    }
    const unsigned short* As = (const unsigned short*)(smem + cur * 16384);
    const unsigned short* Bs = (const unsigned short*)(smem + cur * 16384 + 8192);
    s16x8 af[4], bf[4];
#pragma unroll
    for (int i = 0; i < 4; ++i)
      af[i] = *(const s16x8*)&As[(wr * 64 + i * 16 + l15) * 32 + l16 * 8];
#pragma unroll
    for (int i = 0; i < 4; ++i)
      bf[i] = *(const s16x8*)&Bs[(wc * 64 + i * 16 + l15) * 32 + l16 * 8];
#pragma unroll
    for (int i = 0; i < 4; ++i)
#pragma unroll
      for (int j = 0; j < 4; ++j)
        acc[i][j] = __builtin_amdgcn_mfma_f32_16x16x32_bf16(af[i], bf[j], acc[i][j], 0, 0, 0);
    __syncthreads();
    cur ^= 1;
  }

  if (MODE == 0) {
    unsigned short* T = (unsigned short*)smem;
#pragma unroll
    for (int i = 0; i < 4; ++i)
#pragma unroll
      for (int j = 0; j < 4; ++j) {
        int n = wc * 64 + j * 16 + l15;
        float bv = bias[tileN + n];
#pragma unroll
        for (int r = 0; r < 4; ++r) {
          int m = wr * 64 + i * 16 + l16 * 4 + r;
          *(unsigned short*)((char*)T + m * 256 + ((n * 2) ^ ((m & 15) << 4))) =
              f2bf((acc[i][j][r] + bv) * scl);
        }
      }
    __syncthreads();
    {
      int mr = tid >> 1, half = tid & 1;
      int m = tileM + mr;
      int b_ = m >> 11, s_ = m & 2047;
      int h_ = ((tileN + half * 64) >> 6);
      unsigned short* dst = (unsigned short*)Cout + ((size_t)(b_ * H + h_) * S + s_) * 64;
#pragma unroll
      for (int k = 0; k < 8; ++k) {
        u16x8 v = *(const u16x8*)((const char*)T + mr * 256 +
                                  ((half * 128 + k * 16) ^ ((mr & 15) << 4)));
        *(u16x8*)(dst + k * 8) = v;
      }
    }
  } else if (MODE == 2) {
    unsigned short* T = (unsigned short*)smem;
#pragma unroll
    for (int i = 0; i < 4; ++i)
#pragma unroll
      for (int j = 0; j < 4; ++j) {
        int n = wc * 64 + j * 16 + l15;
        float bv = bias[tileN + n];
        int m0 = wr * 64 + i * 16 + l16 * 4;
        u16x4 o;
#pragma unroll
        for (int r = 0; r < 4; ++r) o[r] = f2bf(acc[i][j][r] + bv);
        *(u16x4*)((char*)T + n * 256 + ((m0 * 2) ^ ((n & 15) << 4))) = o;
      }
    __syncthreads();
    {
      int n = tid >> 1, mh = tid & 1;
      int d = (tileN + n) & 63, h_ = (tileN + n) >> 6;
      int b_ = tileM >> 11;
      int kt_ = (((tileM & 2047) + mh * 64) >> 6);
      unsigned short* dst = (unsigned short*)Cout + (size_t)(b_ * H + h_) * S * 64 +
                            (size_t)kt_ * 4096 + d * 64;
#pragma unroll
      for (int k = 0; k < 8; ++k) {
        int mc = mh * 64 + k * 8;
        u16x8 v = *(const u16x8*)((const char*)T + n * 256 + ((mc * 2) ^ ((n & 15) << 4)));
        *(u16x8*)(dst + k * 8) = v;
      }
    }
  } else {
#pragma unroll
    for (int i = 0; i < 4; ++i) {
#pragma unroll
      for (int j = 0; j < 4; ++j) {
        int n = tileN + wc * 64 + j * 16 + l15;
        float bv = bias[n];
#pragma unroll
        for (int r = 0; r < 4; ++r) {
          int m = tileM + wr * 64 + i * 16 + l16 * 4 + r;
          ((float*)Cout)[(size_t)m * 1024 + n] = (acc[i][j][r] + bv) * scl;
        }
      }
    }
  }
}

__global__ __launch_bounds__(256) void k_gemm_qkv(
    const unsigned short* __restrict__ Xq, const unsigned short* __restrict__ Xk,
    const unsigned short* __restrict__ Xv,
    const unsigned short* __restrict__ Wq, const unsigned short* __restrict__ Wk,
    const unsigned short* __restrict__ Wv,
    const float* __restrict__ bq, const float* __restrict__ bk, const float* __restrict__ bv,
    unsigned short* __restrict__ oq, unsigned short* __restrict__ ok,
    unsigned short* __restrict__ vt2) {
  __shared__ alignas(16) char smem[32768];
  int flat = (blockIdx.z * 32 + blockIdx.y) * 8 + blockIdx.x;
  int swz = (flat & 7) * 96 + (flat >> 3);
  int z = swz >> 8;
  int rem = swz & 255;
  int ty = rem >> 3, tx = rem & 7;
  if (z == 2) {
    gemm_tile<2>(Xv, Wv, bv, vt2, ty * 128, tx * 128, 1.0f, smem);
  } else {
    const unsigned short* A = z == 0 ? Xq : Xk;
    const unsigned short* W = z == 0 ? Wq : Wk;
    const float* bias = z == 0 ? bq : bk;
    unsigned short* o = z == 0 ? oq : ok;
    gemm_tile<0>(A, W, bias, o, ty * 128, tx * 128, z == 0 ? 0.125f : 1.0f, smem);
  }
}

__global__ __launch_bounds__(256) void k_gemm_out(const unsigned short* __restrict__ A,
                                                  const unsigned short* __restrict__ W,
                                                  const float* __restrict__ bias,
                                                  float* __restrict__ Cout) {
  __shared__ alignas(16) char smem[32768];
  int flat = blockIdx.y * 8 + blockIdx.x;
  int swz = (flat & 7) * 32 + (flat >> 3);
  int ty = swz >> 3, tx = swz & 7;
  gemm_tile<1>(A, W, bias, Cout, ty * 128, tx * 128, 1.0f, smem);
}

// ---- O epilogue: cross-wave reduce + normalize + store; writes nl2l to LDS ----
DEVINL void o_epilogue(char* lds, float* lsumW, float* lsumT, float* nl2l,
                       const f32x16& oT0, const f32x16& oT1, float lsum,
                       int tid, int w, int l31, int hi,
                       unsigned short* __restrict__ aout, int b, int q0base, int h) {
  lsum += __shfl_xor(lsum, 32);
  if (hi == 0) lsumW[w * 32 + l31] = lsum;
  const int sqq = (l31 & 15) << 4;
  {
    char* orow = lds + w * 8192 + l31 * 256;
#pragma unroll
    for (int rg = 0; rg < 4; ++rg) {
      f32x4 c0, c1;
#pragma unroll
      for (int j = 0; j < 4; ++j) { c0[j] = oT0[rg * 4 + j]; c1[j] = oT1[rg * 4 + j]; }
      *(f32x4*)(orow + ((rg * 32 + hi * 16) ^ sqq)) = c0;
      *(f32x4*)(orow + ((128 + rg * 32 + hi * 16) ^ sqq)) = c1;
    }
  }
  __syncthreads();
  if (tid < 64) {
    int qg_ = tid >> 5, qq = tid & 31;
    float tot = lsumW[qg_ * 64 + qq] + lsumW[qg_ * 64 + 32 + qq];
    lsumT[tid] = tot;
    nl2l[tid] = __log2f(tot);
  }
  __syncthreads();
  {
    int q = tid >> 2, dq = tid & 3;
    int qg_ = q >> 5, qq = q & 31;
    float inv = 1.f / lsumT[q];
    int sq = (qq & 15) << 4;
    float s[16] = {};
#pragma unroll
    for (int w2 = 0; w2 < 2; ++w2) {
      const char* prow = lds + (qg_ * 2 + w2) * 8192 + qq * 256;
#pragma unroll
      for (int c = 0; c < 4; ++c) {
        f32x4 a = *(const f32x4*)(prow + ((dq * 64 + c * 16) ^ sq));
#pragma unroll
        for (int j = 0; j < 4; ++j) s[c * 4 + j] += a[j];
      }
    }
    u16x8 ob0, ob1;
#pragma unroll
    for (int j = 0; j < 8; ++j) { ob0[j] = f2bf(s[j] * inv); ob1[j] = f2bf(s[8 + j] * inv); }
    unsigned short* abase = aout + ((size_t)b * S + q0base + q) * D + h * 64 + dq * 16;
    *(u16x8*)abase = ob0;
    *(u16x8*)(abase + 8) = ob1;
  }
  __syncthreads();   // LDS (partials region) free for reuse after this
}

// ============ fused attention, X/Y-paired: P2(X) overlaps P1(Y) ==============
// grid 512 (16 q-pairs x 32 bh), 4 waves; block owns X = 64 q, Y = next 64 q.
// Sweep 1: P1(X) (round-13 verified). Sweep 2: per staged tile, the SAME 4
// swizzled LDS K-fragments feed sT_Y = mfma(ka,qfY) (swapped) AND
// dacc_X = mfma(qfX,ka) (unswapped, identical lane layout) -> X's weight
// stores issue between Y's MFMAs (write drain hidden; K from LDS not global).
// Sweep 3: P2(Y) from global K (round-13 verified).
__global__ __launch_bounds__(256) void k_attn_fused(const unsigned short* __restrict__ qw,
                                                    const unsigned short* __restrict__ kw,
                                                    const unsigned short* __restrict__ vt2,
                                                    const int* __restrict__ mask,
                                                    unsigned short* __restrict__ aout,
                                                    float* __restrict__ attw) {
  __shared__ alignas(16) char lds[34048];
  float* lsumW = (float*)(lds + 32768);   // [4][32]
  float* lsumT = (float*)(lds + 33280);   // [64]
  float* nl2lX = (float*)(lds + 33536);   // [64]
  float* nl2lY = (float*)(lds + 33792);   // [64]
  const float LOG2E = 1.44269504f;

  int flat = blockIdx.y * 16 + blockIdx.x;              // 512 blocks
  int swzb = (flat & 7) * 64 + (flat >> 3);             // bijective XCD chunks
  const int bh = swzb >> 4, b = bh >> 4, h = bh & 15;
  const int q0 = (swzb & 15) * 128;
  const int tid = threadIdx.x;
  const int lane = tid & 63, w = tid >> 6;
  const int l31 = lane & 31, hi = lane >> 5;
  const int qg = w >> 1, kb = w & 1;

  const unsigned short* kw_bh = kw + (size_t)bh * S * 64;
  const unsigned short* vt_bh = vt2 + (size_t)bh * S * 64;
  const int* mrow = mask + b * S;

  s16x8 qfX[4], qfY[4];
  {
    const unsigned short* qbX = qw + ((size_t)bh * S + q0 + qg * 32 + l31) * 64 + hi * 8;
    const unsigned short* qbY = qbX + (size_t)64 * 64;
#pragma unroll
    for (int kc = 0; kc < 4; ++kc) {
      qfX[kc] = *(const s16x8*)(qbX + kc * 16);
      qfY[kc] = *(const s16x8*)(qbY + kc * 16);
    }
  }

  // ================= sweep 1: P1(X) =================
  f32x16 oTX0 = {}, oTX1 = {};
  float lsumX = 0.f;
  const int swv = (l31 & 7) << 4;

#pragma unroll
  for (int p = 0; p < 2; ++p) {
    int c = tid + p * 256, row = c >> 3, cc = (c & 7) ^ (row & 7);
    gload_lds16(kw_bh + (size_t)row * 64 + cc * 8, lds + c * 16);
    gload_lds16(vt_bh + (size_t)row * 64 + cc * 8, lds + 16384 + c * 16);
  }
  __syncthreads();

  int cur = 0;
  for (int t = 0; t < 32; ++t) {
    if (t + 1 < 32) {
      int nt = t + 1, nxt = (cur ^ 1) * 8192;
#pragma unroll
      for (int p = 0; p < 2; ++p) {
        int c = tid + p * 256, row = c >> 3, cc = (c & 7) ^ (row & 7);
        gload_lds16(kw_bh + ((size_t)(nt * 64 + row)) * 64 + cc * 8, lds + nxt + c * 16);
        gload_lds16(vt_bh + (size_t)nt * 4096 + row * 64 + cc * 8, lds + 16384 + nxt + c * 16);
      }
    }
    const char* Kc = lds + cur * 8192;
    const char* Vc = lds + 16384 + cur * 8192;
    const int krow = kb * 32 + l31;

    f32x16 sT = {};
#pragma unroll
    for (int kc = 0; kc < 4; ++kc) {
      s16x8 ka = *(const s16x8*)(Kc + krow * 128 + ((kc * 32 + hi * 16) ^ ((krow & 7) << 4)));
      sT = __builtin_amdgcn_mfma_f32_32x32x16_bf16(ka, qfX[kc], sT, 0, 0, 0);
    }

    int base = t * 64 + kb * 32 + 4 * hi;
    int m[16];
    *(int4*)&m[0]  = *(const int4*)&mrow[base];
    *(int4*)&m[4]  = *(const int4*)&mrow[base + 8];
    *(int4*)&m[8]  = *(const int4*)&mrow[base + 16];
    *(int4*)&m[12] = *(const int4*)&mrow[base + 24];

    float e[16];
#pragma unroll
    for (int r = 0; r < 16; ++r) {
      e[r] = m[r] ? exp2f(sT[r] * LOG2E) : 0.f;
      lsumX += e[r];
    }

    unsigned x0 = cvt_pk_bf16(e[0], e[1]),   x1 = cvt_pk_bf16(e[2], e[3]);
    unsigned x2 = cvt_pk_bf16(e[4], e[5]),   x3 = cvt_pk_bf16(e[6], e[7]);
    unsigned x4 = cvt_pk_bf16(e[8], e[9]),   x5 = cvt_pk_bf16(e[10], e[11]);
    unsigned x6 = cvt_pk_bf16(e[12], e[13]), x7 = cvt_pk_bf16(e[14], e[15]);
    perm32swap(x0, x2); perm32swap(x1, x3);
    perm32swap(x4, x6); perm32swap(x5, x7);
    union { unsigned u[4]; s16x8 v; } p0u, p1u;
    p0u.u[0] = x0; p0u.u[1] = x1; p0u.u[2] = x2; p0u.u[3] = x3;
    p1u.u[0] = x4; p1u.u[1] = x5; p1u.u[2] = x6; p1u.u[3] = x7;

    const int ko0 = kb * 64 + hi * 16, ko1 = kb * 64 + 32 + hi * 16;
    const char* Vr0 = Vc + l31 * 128;
    const char* Vr1 = Vc + (32 + l31) * 128;
    s16x8 va;
    va = *(const s16x8*)(Vr0 + (ko0 ^ swv));
    oTX0 = __builtin_amdgcn_mfma_f32_32x32x16_bf16(va, p0u.v, oTX0, 0, 0, 0);
    va = *(const s16x8*)(Vr0 + (ko1 ^ swv));
    oTX0 = __builtin_amdgcn_mfma_f32_32x32x16_bf16(va, p1u.v, oTX0, 0, 0, 0);
    va = *(const s16x8*)(Vr1 + (ko0 ^ swv));
    oTX1 = __builtin_amdgcn_mfma_f32_32x32x16_bf16(va, p0u.v, oTX1, 0, 0, 0);
    va = *(const s16x8*)(Vr1 + (ko1 ^ swv));
    oTX1 = __builtin_amdgcn_mfma_f32_32x32x16_bf16(va, p1u.v, oTX1, 0, 0, 0);

    __syncthreads();
    cur ^= 1;
  }
  o_epilogue(lds, lsumW, lsumT, nl2lX, oTX0, oTX1, lsumX, tid, w, l31, hi, aout, b, q0, h);

  float nl2lXr[16];
#pragma unroll
  for (int r = 0; r < 16; ++r) nl2lXr[r] = nl2lX[qg * 32 + (r & 3) + 8 * (r >> 2) + 4 * hi];

  // ================= sweep 2: P1(Y) + P2(X) interleaved =================
  f32x16 oTY0 = {}, oTY1 = {};
  float lsumY = 0.f;

#pragma unroll
  for (int p = 0; p < 2; ++p) {
    int c = tid + p * 256, row = c >> 3, cc = (c & 7) ^ (row & 7);
    gload_lds16(kw_bh + (size_t)row * 64 + cc * 8, lds + c * 16);
    gload_lds16(vt_bh + (size_t)row * 64 + cc * 8, lds + 16384 + c * 16);
  }
  __syncthreads();

  cur = 0;
  for (int t = 0; t < 32; ++t) {
    if (t + 1 < 32) {
      int nt = t + 1, nxt = (cur ^ 1) * 8192;
#pragma unroll
      for (int p = 0; p < 2; ++p) {
        int c = tid + p * 256, row = c >> 3, cc = (c & 7) ^ (row & 7);
        gload_lds16(kw_bh + ((size_t)(nt * 64 + row)) * 64 + cc * 8, lds + nxt + c * 16);
        gload_lds16(vt_bh + (size_t)nt * 4096 + row * 64 + cc * 8, lds + 16384 + nxt + c * 16);
      }
    }
    const char* Kc = lds + cur * 8192;
    const char* Vc = lds + 16384 + cur * 8192;
    const int krow = kb * 32 + l31;

    // shared K fragments: A-operand for sT_Y, B-operand for dacc_X (same layout)
    s16x8 ka[4];
#pragma unroll
    for (int kc = 0; kc < 4; ++kc)
      ka[kc] = *(const s16x8*)(Kc + krow * 128 + ((kc * 32 + hi * 16) ^ ((krow & 7) << 4)));

    f32x16 sT = {}, dX = {};
#pragma unroll
    for (int kc = 0; kc < 4; ++kc) {
      sT = __builtin_amdgcn_mfma_f32_32x32x16_bf16(ka[kc], qfY[kc], sT, 0, 0, 0);
      dX = __builtin_amdgcn_mfma_f32_32x32x16_bf16(qfX[kc], ka[kc], dX, 0, 0, 0);
    }

    int base = t * 64 + kb * 32 + 4 * hi;
    int m[16];
    *(int4*)&m[0]  = *(const int4*)&mrow[base];
    *(int4*)&m[4]  = *(const int4*)&mrow[base + 8];
    *(int4*)&m[8]  = *(const int4*)&mrow[base + 16];
    *(int4*)&m[12] = *(const int4*)&mrow[base + 24];
    int mk = mrow[t * 64 + kb * 32 + l31];

    // X weights: w = exp2(s - log2lsumX), coalesced nontemporal stores
    {
      float* obase = attw + ((size_t)bh * S + q0 + qg * 32) * S + t * 64 + kb * 32 + l31;
#pragma unroll
      for (int r = 0; r < 16; ++r) {
        int row = (r & 3) + 8 * (r >> 2) + 4 * hi;
        float wv = mk ? exp2f(dX[r] * LOG2E - nl2lXr[r]) : 0.f;
        __builtin_nontemporal_store(wv, obase + (size_t)row * S);
      }
    }

    float e[16];
#pragma unroll
    for (int r = 0; r < 16; ++r) {
      e[r] = m[r] ? exp2f(sT[r] * LOG2E) : 0.f;
      lsumY += e[r];
    }

    unsigned x0 = cvt_pk_bf16(e[0], e[1]),   x1 = cvt_pk_bf16(e[2], e[3]);
    unsigned x2 = cvt_pk_bf16(e[4], e[5]),   x3 = cvt_pk_bf16(e[6], e[7]);
    unsigned x4 = cvt_pk_bf16(e[8], e[9]),   x5 = cvt_pk_bf16(e[10], e[11]);
    unsigned x6 = cvt_pk_bf16(e[12], e[13]), x7 = cvt_pk_bf16(e[14], e[15]);
    perm32swap(x0, x2); perm32swap(x1, x3);
    perm32swap(x4, x6); perm32swap(x5, x7);
    union { unsigned u[4]; s16x8 v; } p0u, p1u;
    p0u.u[0] = x0; p0u.u[1] = x1; p0u.u[2] = x2; p0u.u[3] = x3;
    p1u.u[0] = x4; p1u.u[1] = x5; p1u.u[2] = x6; p1u.u[3] = x7;

    const int ko0 = kb * 64 + hi * 16, ko1 = kb * 64 + 32 + hi * 16;
    const char* Vr0 = Vc + l31 * 128;
    const char* Vr1 = Vc + (32 + l31) * 128;
    s16x8 va;
    va = *(const s16x8*)(Vr0 + (ko0 ^ swv));
    oTY0 = __builtin_amdgcn_mfma_f32_32x32x16_bf16(va, p0u.v, oTY0, 0, 0, 0);
    va = *(const s16x8*)(Vr0 + (ko1 ^ swv));
    oTY0 = __builtin_amdgcn_mfma_f32_32x32x16_bf16(va, p1u.v, oTY0, 0, 0, 0);
    va = *(const s16x8*)(Vr1 + (ko0 ^ swv));
    oTY1 = __builtin_amdgcn_mfma_f32_32x32x16_bf16(va, p0u.v, oTY1, 0, 0, 0);
    va = *(const s16x8*)(Vr1 + (ko1 ^ swv));
    oTY1 = __builtin_amdgcn_mfma_f32_32x32x16_bf16(va, p1u.v, oTY1, 0, 0, 0);

    __syncthreads();
    cur ^= 1;
  }
  o_epilogue(lds, lsumW, lsumT, nl2lY, oTY0, oTY1, lsumY, tid, w, l31, hi, aout, b, q0 + 64, h);

  float nl2lYr[16];
#pragma unroll
  for (int r = 0; r < 16; ++r) nl2lYr[r] = nl2lY[qg * 32 + (r & 3) + 8 * (r >> 2) + 4 * hi];

  // ================= sweep 3: P2(Y) from global K =================
  for (int it = 0; it < 32; ++it) {
    int key0 = it * 64 + kb * 32;
    const unsigned short* kbase = kw_bh + (size_t)(key0 + l31) * 64 + hi * 8;
    s16x8 kfr[4];
#pragma unroll
    for (int kc = 0; kc < 4; ++kc) kfr[kc] = *(const s16x8*)(kbase + kc * 16);
    f32x16 dacc = {};
#pragma unroll
    for (int kc = 0; kc < 4; ++kc)
      dacc = __builtin_amdgcn_mfma_f32_32x32x16_bf16(qfY[kc], kfr[kc], dacc, 0, 0, 0);

    int key = key0 + l31;
    int mk = mrow[key];
    float* obase = attw + ((size_t)bh * S + q0 + 64 + qg * 32) * S + key;
#pragma unroll
    for (int r = 0; r < 16; ++r) {
      int row = (r & 3) + 8 * (r >> 2) + 4 * hi;
      float wv = mk ? exp2f(dacc[r] * LOG2E - nl2lYr[r]) : 0.f;
      __builtin_nontemporal_store(wv, obase + (size_t)row * S);
    }
  }
}

// ---------------- host ----------------
extern "C" void kernel_launch(void* const* d_in, const int* in_sizes, int n_in,
                              void* d_out, int out_size, void* d_ws, size_t ws_size,
                              hipStream_t stream) {
  (void)in_sizes; (void)n_in; (void)out_size; (void)ws_size;
  const float* Q  = (const float*)d_in[0];
  const float* K  = (const float*)d_in[1];
  const float* V  = (const float*)d_in[2];
  const int* mask = (const int*)d_in[3];
  const float* Wq = (const float*)d_in[4];
  const float* bq = (const float*)d_in[5];
  const float* Wk = (const float*)d_in[6];
  const float* bk = (const float*)d_in[7];
  const float* Wv = (const float*)d_in[8];
  const float* bv = (const float*)d_in[9];
  const float* Wo = (const float*)d_in[10];
  const float* bo = (const float*)d_in[11];

  char* ws = (char*)d_ws;
  unsigned short* Xbf  = (unsigned short*)(ws + 0);           // [3][4194304] bf16
  unsigned short* Wbf  = (unsigned short*)(ws + 25165824);    // [4][1048576] bf16
  unsigned short* qws  = (unsigned short*)(ws + 33554432);    // [bh][s][64]
  unsigned short* kws  = (unsigned short*)(ws + 41943040);    // [bh][s][64]
  unsigned short* vt2  = (unsigned short*)(ws + 50331648);    // [bh][kt][64][64]
  unsigned short* aoutb= (unsigned short*)(ws + 8388608);     // reuse Xbf[K] (consumed)
  float* out0 = (float*)d_out;
  float* attw = (float*)d_out + OUT0;

  k_cvt_all<<<dim3(8192), dim3(256), 0, stream>>>(
      Q, K, V, Wq, Wk, Wv, Wo,
      Xbf, Xbf + 4194304, Xbf + 8388608,
      Wbf, Wbf + 1048576, Wbf + 2097152, Wbf + 3145728);

  k_gemm_qkv<<<dim3(8, 32, 3), dim3(256), 0, stream>>>(
      Xbf, Xbf + 4194304, Xbf + 8388608,
      Wbf, Wbf + 1048576, Wbf + 2097152,
      bq, bk, bv, qws, kws, vt2);

  k_attn_fused<<<dim3(16, 32), dim3(256), 0, stream>>>(qws, kws, vt2, mask, aoutb, attw);

  k_gemm_out<<<dim3(8, 32), dim3(256), 0, stream>>>(aoutb, Wbf + 3145728, bo, out0);
}

// Round 16
// 230.116 us; speedup vs baseline: 1.1766x; 1.1766x over previous
//
#include <hip/hip_runtime.h>
#include <stdint.h>

#define DEVINL __device__ __forceinline__

typedef float  f32x4  __attribute__((ext_vector_type(4)));
typedef float  f32x16 __attribute__((ext_vector_type(16)));
typedef short  s16x8  __attribute__((ext_vector_type(8)));
typedef unsigned short u16x4 __attribute__((ext_vector_type(4)));
typedef unsigned short u16x8 __attribute__((ext_vector_type(8)));

static constexpr int S = 2048, D = 1024, H = 16;
static constexpr size_t OUT0 = (size_t)2 * S * D;   // 4194304

DEVINL unsigned short f2bf(float f) {
  union { float f; unsigned u; } v; v.f = f;
  unsigned r = v.u + 0x7FFFu + ((v.u >> 16) & 1u);   // RNE
  return (unsigned short)(r >> 16);
}

DEVINL unsigned cvt_pk_bf16(float lo, float hi) {
  unsigned r;
  asm("v_cvt_pk_bf16_f32 %0, %1, %2" : "=v"(r) : "v"(lo), "v"(hi));
  return r;
}

DEVINL void perm32swap(unsigned& a, unsigned& b) {
#if __has_builtin(__builtin_amdgcn_permlane32_swap)
  auto r = __builtin_amdgcn_permlane32_swap(a, b, false, false);
  a = r[0]; b = r[1];
#else
  asm volatile("v_permlane32_swap_b32 %0, %1" : "+v"(a), "+v"(b));
#endif
}

DEVINL void gload_lds16(const void* g, void* l) {
  __builtin_amdgcn_global_load_lds(
      (const __attribute__((address_space(1))) unsigned int*)g,
      (__attribute__((address_space(3))) unsigned int*)l, 16, 0, 0);
}

// ---------------- fp32 -> bf16 convert, single launch for all 7 tensors ------
DEVINL void cvt_body(const float* __restrict__ src, unsigned short* __restrict__ dst, int i) {
  const f32x4* s4 = (const f32x4*)src;
  f32x4 a = s4[i * 2], b = s4[i * 2 + 1];
  u16x8 o;
  o[0] = f2bf(a[0]); o[1] = f2bf(a[1]); o[2] = f2bf(a[2]); o[3] = f2bf(a[3]);
  o[4] = f2bf(b[0]); o[5] = f2bf(b[1]); o[6] = f2bf(b[2]); o[7] = f2bf(b[3]);
  ((u16x8*)dst)[i] = o;
}

__global__ __launch_bounds__(256) void k_cvt_all(
    const float* __restrict__ Q, const float* __restrict__ K, const float* __restrict__ V,
    const float* __restrict__ Wq, const float* __restrict__ Wk,
    const float* __restrict__ Wv, const float* __restrict__ Wo,
    unsigned short* __restrict__ Xq, unsigned short* __restrict__ Xk,
    unsigned short* __restrict__ Xv,
    unsigned short* __restrict__ WQ, unsigned short* __restrict__ WK,
    unsigned short* __restrict__ WV, unsigned short* __restrict__ WO) {
  int i = blockIdx.x;
  const float* src; unsigned short* dst; int item;
  if (i < 6144) {                       // Q,K,V: 2048 blocks each
    int z = i >> 11;
    item = (i & 2047) * 256 + threadIdx.x;
    src = z == 0 ? Q : z == 1 ? K : V;
    dst = z == 0 ? Xq : z == 1 ? Xk : Xv;
  } else {                              // Wq,Wk,Wv,Wo: 512 blocks each
    int j = i - 6144, z = j >> 9;
    item = (j & 511) * 256 + threadIdx.x;
    src = z == 0 ? Wq : z == 1 ? Wk : z == 2 ? Wv : Wo;
    dst = z == 0 ? WQ : z == 1 ? WK : z == 2 ? WV : WO;
  }
  cvt_body(src, dst, item);
}

// ------- GEMM core: C[128,128] tile, BK=32, DOUBLE-BUFFERED prefetch ---------
// MODE 0: bf16 -> [b,h,s,d] with scale, via LDS-bounce coalesced stores.
// MODE 1: fp32 row-major direct. MODE 2: bf16 -> vt2 [bh][kt][64 d][64 s] bounce.
template <int MODE>
DEVINL void gemm_tile(const unsigned short* __restrict__ A,
                      const unsigned short* __restrict__ Bw,
                      const float* __restrict__ bias, void* __restrict__ Cout,
                      int tileM, int tileN, float scl, char* smem) {
  const int tid = threadIdx.x;
  const int lane = tid & 63, wave = tid >> 6;
  const int wr = wave >> 1, wc = wave & 1;
  const int l15 = lane & 15, l16 = lane >> 4;
  f32x4 acc[4][4] = {};

  // prologue: stage k0=0 into buffer 0
#pragma unroll
  for (int p = 0; p < 2; ++p) {
    int c = tid + p * 256;
    int row = c >> 2, col = (c & 3) * 8;
    gload_lds16(A + (((size_t)(tileM + row)) << 10) + col, smem + c * 16);
    gload_lds16(Bw + (((size_t)(tileN + row)) << 10) + col, smem + 8192 + c * 16);
  }
  __syncthreads();

  int cur = 0;
  for (int k0 = 0; k0 < 1024; k0 += 32) {
    if (k0 + 32 < 1024) {   // prefetch next K-slab (overlaps compute below)
      int nxt = (cur ^ 1) * 16384;
#pragma unroll
      for (int p = 0; p < 2; ++p) {
        int c = tid + p * 256;
        int row = c >> 2, col = (c & 3) * 8;
        gload_lds16(A + (((size_t)(tileM + row)) << 10) + k0 + 32 + col, smem + nxt + c * 16);
        gload_lds16(Bw + (((size_t)(tileN + row)) << 10) + k0 + 32 + col, smem + nxt + 8192 + c * 16);
      }
    }
    const unsigned short* As = (const unsigned short*)(smem + cur * 16384);
    const unsigned short* Bs = (const unsigned short*)(smem + cur * 16384 + 8192);
    s16x8 af[4], bf[4];
#pragma unroll
    for (int i = 0; i < 4; ++i)
      af[i] = *(const s16x8*)&As[(wr * 64 + i * 16 + l15) * 32 + l16 * 8];
#pragma unroll
    for (int i = 0; i < 4; ++i)
      bf[i] = *(const s16x8*)&Bs[(wc * 64 + i * 16 + l15) * 32 + l16 * 8];
#pragma unroll
    for (int i = 0; i < 4; ++i)
#pragma unroll
      for (int j = 0; j < 4; ++j)
        acc[i][j] = __builtin_amdgcn_mfma_f32_16x16x32_bf16(af[i], bf[j], acc[i][j], 0, 0, 0);
    __syncthreads();   // prefetch landed (vmcnt), all waves done with cur
    cur ^= 1;
  }

  if (MODE == 0) {
    // LDS-bounce: T[m 128][n 128] bf16 (256B rows), swizzle byte ^= (m&15)<<4.
    unsigned short* T = (unsigned short*)smem;
#pragma unroll
    for (int i = 0; i < 4; ++i)
#pragma unroll
      for (int j = 0; j < 4; ++j) {
        int n = wc * 64 + j * 16 + l15;
        float bv = bias[tileN + n];
#pragma unroll
        for (int r = 0; r < 4; ++r) {
          int m = wr * 64 + i * 16 + l16 * 4 + r;
          *(unsigned short*)((char*)T + m * 256 + ((n * 2) ^ ((m & 15) << 4))) =
              f2bf((acc[i][j][r] + bv) * scl);
        }
      }
    __syncthreads();
    {
      int mr = tid >> 1, half = tid & 1;
      int m = tileM + mr;
      int b_ = m >> 11, s_ = m & 2047;
      int h_ = ((tileN + half * 64) >> 6);
      unsigned short* dst = (unsigned short*)Cout + ((size_t)(b_ * H + h_) * S + s_) * 64;
#pragma unroll
      for (int k = 0; k < 8; ++k) {
        u16x8 v = *(const u16x8*)((const char*)T + mr * 256 +
                                  ((half * 128 + k * 16) ^ ((mr & 15) << 4)));
        *(u16x8*)(dst + k * 8) = v;
      }
    }
  } else if (MODE == 2) {
    // LDS-bounce transpose: T[n 128][m 128] bf16 (256B rows), swz (n&15)<<4.
    unsigned short* T = (unsigned short*)smem;
#pragma unroll
    for (int i = 0; i < 4; ++i)
#pragma unroll
      for (int j = 0; j < 4; ++j) {
        int n = wc * 64 + j * 16 + l15;
        float bv = bias[tileN + n];
        int m0 = wr * 64 + i * 16 + l16 * 4;
        u16x4 o;
#pragma unroll
        for (int r = 0; r < 4; ++r) o[r] = f2bf(acc[i][j][r] + bv);
        *(u16x4*)((char*)T + n * 256 + ((m0 * 2) ^ ((n & 15) << 4))) = o;
      }
    __syncthreads();
    {
      int n = tid >> 1, mh = tid & 1;
      int d = (tileN + n) & 63, h_ = (tileN + n) >> 6;
      int b_ = tileM >> 11;
      int kt_ = (((tileM & 2047) + mh * 64) >> 6);
      unsigned short* dst = (unsigned short*)Cout + (size_t)(b_ * H + h_) * S * 64 +
                            (size_t)kt_ * 4096 + d * 64;
#pragma unroll
      for (int k = 0; k < 8; ++k) {
        int mc = mh * 64 + k * 8;
        u16x8 v = *(const u16x8*)((const char*)T + n * 256 + ((mc * 2) ^ ((n & 15) << 4)));
        *(u16x8*)(dst + k * 8) = v;
      }
    }
  } else {
#pragma unroll
    for (int i = 0; i < 4; ++i) {
#pragma unroll
      for (int j = 0; j < 4; ++j) {
        int n = tileN + wc * 64 + j * 16 + l15;
        float bv = bias[n];
#pragma unroll
        for (int r = 0; r < 4; ++r) {
          int m = tileM + wr * 64 + i * 16 + l16 * 4 + r;
          ((float*)Cout)[(size_t)m * 1024 + n] = (acc[i][j][r] + bv) * scl;
        }
      }
    }
  }
}

// Fused QKV projection, XCD-swizzled. z=0 Q (pre-scaled 1/8), z=1 K, z=2 V->vt2.
__global__ __launch_bounds__(256) void k_gemm_qkv(
    const unsigned short* __restrict__ Xq, const unsigned short* __restrict__ Xk,
    const unsigned short* __restrict__ Xv,
    const unsigned short* __restrict__ Wq, const unsigned short* __restrict__ Wk,
    const unsigned short* __restrict__ Wv,
    const float* __restrict__ bq, const float* __restrict__ bk, const float* __restrict__ bv,
    unsigned short* __restrict__ oq, unsigned short* __restrict__ ok,
    unsigned short* __restrict__ vt2) {
  __shared__ alignas(16) char smem[32768];
  int flat = (blockIdx.z * 32 + blockIdx.y) * 8 + blockIdx.x;   // [0,768)
  int swz = (flat & 7) * 96 + (flat >> 3);                      // bijective (768 = 8*96)
  int z = swz >> 8;
  int rem = swz & 255;
  int ty = rem >> 3, tx = rem & 7;
  if (z == 2) {
    gemm_tile<2>(Xv, Wv, bv, vt2, ty * 128, tx * 128, 1.0f, smem);
  } else {
    const unsigned short* A = z == 0 ? Xq : Xk;
    const unsigned short* W = z == 0 ? Wq : Wk;
    const float* bias = z == 0 ? bq : bk;
    unsigned short* o = z == 0 ? oq : ok;
    gemm_tile<0>(A, W, bias, o, ty * 128, tx * 128, z == 0 ? 0.125f : 1.0f, smem);
  }
}

// Output projection, XCD-swizzled.
__global__ __launch_bounds__(256) void k_gemm_out(const unsigned short* __restrict__ A,
                                                  const unsigned short* __restrict__ W,
                                                  const float* __restrict__ bias,
                                                  float* __restrict__ Cout) {
  __shared__ alignas(16) char smem[32768];
  int flat = blockIdx.y * 8 + blockIdx.x;                        // [0,256)
  int swz = (flat & 7) * 32 + (flat >> 3);                       // bijective (256 = 8*32)
  int ty = swz >> 3, tx = swz & 7;
  gemm_tile<1>(A, W, bias, Cout, ty * 128, tx * 128, 1.0f, smem);
}

// ============ fused attention: O-pass + weights-write, double-buffered ========
// (round-13/14 verified structure — restored after round-15's X/Y pairing
// regressed: 2 blocks/CU + in-wave store/MFMA interleave ran writes at 20% BW)
__global__ __launch_bounds__(256) void k_attn_fused(const unsigned short* __restrict__ qw,
                                                    const unsigned short* __restrict__ kw,
                                                    const unsigned short* __restrict__ vt2,
                                                    const int* __restrict__ mask,
                                                    unsigned short* __restrict__ aout,
                                                    float* __restrict__ attw) {
  __shared__ alignas(16) char lds[33792];
  float* lsumW = (float*)(lds + 32768);   // [4 wave][32 q]
  float* lsumT = (float*)(lds + 33280);   // [64 q]
  float* nl2lW = (float*)(lds + 33536);   // [64 q]
  const float LOG2E = 1.44269504f;

  int flat = blockIdx.y * 32 + blockIdx.x;              // 1024 blocks
  int swzb = (flat & 7) * 128 + (flat >> 3);            // bijective XCD chunks
  const int bh = swzb >> 5, b = bh >> 4, h = bh & 15;
  const int q0 = (swzb & 31) * 64;
  const int tid = threadIdx.x;
  const int lane = tid & 63, w = tid >> 6;
  const int l31 = lane & 31, hi = lane >> 5;
  const int qg = w >> 1, kb = w & 1;

  const unsigned short* kw_bh = kw + (size_t)bh * S * 64;
  const unsigned short* vt_bh = vt2 + (size_t)bh * S * 64;
  const int* mrow = mask + b * S;

  s16x8 qf[4];
  const unsigned short* qbase = qw + ((size_t)bh * S + q0 + qg * 32 + l31) * 64 + hi * 8;
#pragma unroll
  for (int kc = 0; kc < 4; ++kc) qf[kc] = *(const s16x8*)(qbase + kc * 16);

  // ---------------- pass 1 ----------------
  f32x16 oT0 = {}, oT1 = {};
  float lsum = 0.f;
  const int swv = (l31 & 7) << 4;

#pragma unroll
  for (int p = 0; p < 2; ++p) {
    int c = tid + p * 256, row = c >> 3, cc = (c & 7) ^ (row & 7);
    gload_lds16(kw_bh + (size_t)row * 64 + cc * 8, lds + c * 16);
    gload_lds16(vt_bh + (size_t)row * 64 + cc * 8, lds + 16384 + c * 16);
  }
  __syncthreads();

  int cur = 0;
  for (int t = 0; t < 32; ++t) {
    if (t + 1 < 32) {
      int nt = t + 1;
      int nxt = (cur ^ 1) * 8192;
#pragma unroll
      for (int p = 0; p < 2; ++p) {
        int c = tid + p * 256, row = c >> 3, cc = (c & 7) ^ (row & 7);
        gload_lds16(kw_bh + ((size_t)(nt * 64 + row)) * 64 + cc * 8, lds + nxt + c * 16);
        gload_lds16(vt_bh + (size_t)nt * 4096 + row * 64 + cc * 8, lds + 16384 + nxt + c * 16);
      }
    }
    const char* Kc = lds + cur * 8192;
    const char* Vc = lds + 16384 + cur * 8192;

    const int krow = kb * 32 + l31;
    f32x16 sT = {};
#pragma unroll
    for (int kc = 0; kc < 4; ++kc) {
      s16x8 ka = *(const s16x8*)(Kc + krow * 128 +
                                 ((kc * 32 + hi * 16) ^ ((krow & 7) << 4)));
      sT = __builtin_amdgcn_mfma_f32_32x32x16_bf16(ka, qf[kc], sT, 0, 0, 0);
    }

    int base = t * 64 + kb * 32 + 4 * hi;
    int m[16];
    *(int4*)&m[0]  = *(const int4*)&mrow[base];
    *(int4*)&m[4]  = *(const int4*)&mrow[base + 8];
    *(int4*)&m[8]  = *(const int4*)&mrow[base + 16];
    *(int4*)&m[12] = *(const int4*)&mrow[base + 24];

    float e[16];
#pragma unroll
    for (int r = 0; r < 16; ++r) {
      e[r] = m[r] ? exp2f(sT[r] * LOG2E) : 0.f;
      lsum += e[r];
    }

    unsigned x0 = cvt_pk_bf16(e[0], e[1]),   x1 = cvt_pk_bf16(e[2], e[3]);
    unsigned x2 = cvt_pk_bf16(e[4], e[5]),   x3 = cvt_pk_bf16(e[6], e[7]);
    unsigned x4 = cvt_pk_bf16(e[8], e[9]),   x5 = cvt_pk_bf16(e[10], e[11]);
    unsigned x6 = cvt_pk_bf16(e[12], e[13]), x7 = cvt_pk_bf16(e[14], e[15]);
    perm32swap(x0, x2); perm32swap(x1, x3);
    perm32swap(x4, x6); perm32swap(x5, x7);
    union { unsigned u[4]; s16x8 v; } p0u, p1u;
    p0u.u[0] = x0; p0u.u[1] = x1; p0u.u[2] = x2; p0u.u[3] = x3;
    p1u.u[0] = x4; p1u.u[1] = x5; p1u.u[2] = x6; p1u.u[3] = x7;

    const int ko0 = kb * 64 + hi * 16, ko1 = kb * 64 + 32 + hi * 16;
    const char* Vr0 = Vc + l31 * 128;
    const char* Vr1 = Vc + (32 + l31) * 128;
    s16x8 va;
    va = *(const s16x8*)(Vr0 + (ko0 ^ swv));
    oT0 = __builtin_amdgcn_mfma_f32_32x32x16_bf16(va, p0u.v, oT0, 0, 0, 0);
    va = *(const s16x8*)(Vr0 + (ko1 ^ swv));
    oT0 = __builtin_amdgcn_mfma_f32_32x32x16_bf16(va, p1u.v, oT0, 0, 0, 0);
    va = *(const s16x8*)(Vr1 + (ko0 ^ swv));
    oT1 = __builtin_amdgcn_mfma_f32_32x32x16_bf16(va, p0u.v, oT1, 0, 0, 0);
    va = *(const s16x8*)(Vr1 + (ko1 ^ swv));
    oT1 = __builtin_amdgcn_mfma_f32_32x32x16_bf16(va, p1u.v, oT1, 0, 0, 0);

    __syncthreads();
    cur ^= 1;
  }

  lsum += __shfl_xor(lsum, 32);
  if (hi == 0) lsumW[w * 32 + l31] = lsum;

  const int sqq = (l31 & 15) << 4;
  {
    char* orow = lds + w * 8192 + l31 * 256;
#pragma unroll
    for (int rg = 0; rg < 4; ++rg) {
      f32x4 c0, c1;
#pragma unroll
      for (int j = 0; j < 4; ++j) { c0[j] = oT0[rg * 4 + j]; c1[j] = oT1[rg * 4 + j]; }
      *(f32x4*)(orow + ((rg * 32 + hi * 16) ^ sqq)) = c0;
      *(f32x4*)(orow + ((128 + rg * 32 + hi * 16) ^ sqq)) = c1;
    }
  }
  __syncthreads();

  if (tid < 64) {
    int qg_ = tid >> 5, qq = tid & 31;
    float tot = lsumW[qg_ * 64 + qq] + lsumW[qg_ * 64 + 32 + qq];
    lsumT[tid] = tot;
    nl2lW[tid] = __log2f(tot);
  }
  __syncthreads();

  {
    int q = tid >> 2, dq = tid & 3;
    int qg_ = q >> 5, qq = q & 31;
    float inv = 1.f / lsumT[q];
    int sq = (qq & 15) << 4;
    float s[16] = {};
#pragma unroll
    for (int w2 = 0; w2 < 2; ++w2) {
      const char* prow = lds + (qg_ * 2 + w2) * 8192 + qq * 256;
#pragma unroll
      for (int c = 0; c < 4; ++c) {
        f32x4 a = *(const f32x4*)(prow + ((dq * 64 + c * 16) ^ sq));
#pragma unroll
        for (int j = 0; j < 4; ++j) s[c * 4 + j] += a[j];
      }
    }
    u16x8 ob0, ob1;
#pragma unroll
    for (int j = 0; j < 8; ++j) { ob0[j] = f2bf(s[j] * inv); ob1[j] = f2bf(s[8 + j] * inv); }
    unsigned short* abase = aout + ((size_t)b * S + q0 + q) * D + h * 64 + dq * 16;
    *(u16x8*)abase = ob0;
    *(u16x8*)(abase + 8) = ob1;
  }

  // ---------------- pass 2: weights write ----------------
  float nl2l[16];
#pragma unroll
  for (int r = 0; r < 16; ++r) nl2l[r] = nl2lW[qg * 32 + (r & 3) + 8 * (r >> 2) + 4 * hi];

  for (int it = 0; it < 32; ++it) {
    int key0 = it * 64 + kb * 32;
    const unsigned short* kbase = kw_bh + (size_t)(key0 + l31) * 64 + hi * 8;
    s16x8 kfr[4];
#pragma unroll
    for (int kc = 0; kc < 4; ++kc) kfr[kc] = *(const s16x8*)(kbase + kc * 16);
    f32x16 dacc = {};
#pragma unroll
    for (int kc = 0; kc < 4; ++kc)
      dacc = __builtin_amdgcn_mfma_f32_32x32x16_bf16(qf[kc], kfr[kc], dacc, 0, 0, 0);

    int key = key0 + l31;
    int mk = mrow[key];
    float* obase = attw + ((size_t)bh * S + q0 + qg * 32) * S + key;
#pragma unroll
    for (int r = 0; r < 16; ++r) {
      int row = (r & 3) + 8 * (r >> 2) + 4 * hi;
      float wv = mk ? exp2f(dacc[r] * LOG2E - nl2l[r]) : 0.f;
      __builtin_nontemporal_store(wv, obase + (size_t)row * S);
    }
  }
}

// ---------------- host ----------------
extern "C" void kernel_launch(void* const* d_in, const int* in_sizes, int n_in,
                              void* d_out, int out_size, void* d_ws, size_t ws_size,
                              hipStream_t stream) {
  (void)in_sizes; (void)n_in; (void)out_size; (void)ws_size;
  const float* Q  = (const float*)d_in[0];
  const float* K  = (const float*)d_in[1];
  const float* V  = (const float*)d_in[2];
  const int* mask = (const int*)d_in[3];
  const float* Wq = (const float*)d_in[4];
  const float* bq = (const float*)d_in[5];
  const float* Wk = (const float*)d_in[6];
  const float* bk = (const float*)d_in[7];
  const float* Wv = (const float*)d_in[8];
  const float* bv = (const float*)d_in[9];
  const float* Wo = (const float*)d_in[10];
  const float* bo = (const float*)d_in[11];

  char* ws = (char*)d_ws;
  unsigned short* Xbf  = (unsigned short*)(ws + 0);           // [3][4194304] bf16
  unsigned short* Wbf  = (unsigned short*)(ws + 25165824);    // [4][1048576] bf16
  unsigned short* qws  = (unsigned short*)(ws + 33554432);    // [bh][s][64]
  unsigned short* kws  = (unsigned short*)(ws + 41943040);    // [bh][s][64]
  unsigned short* vt2  = (unsigned short*)(ws + 50331648);    // [bh][kt][64][64]
  unsigned short* aoutb= (unsigned short*)(ws + 8388608);     // reuse Xbf[K] (consumed)
  float* out0 = (float*)d_out;
  float* attw = (float*)d_out + OUT0;

  k_cvt_all<<<dim3(8192), dim3(256), 0, stream>>>(
      Q, K, V, Wq, Wk, Wv, Wo,
      Xbf, Xbf + 4194304, Xbf + 8388608,
      Wbf, Wbf + 1048576, Wbf + 2097152, Wbf + 3145728);

  k_gemm_qkv<<<dim3(8, 32, 3), dim3(256), 0, stream>>>(
      Xbf, Xbf + 4194304, Xbf + 8388608,
      Wbf, Wbf + 1048576, Wbf + 2097152,
      bq, bk, bv, qws, kws, vt2);

  k_attn_fused<<<dim3(32, 32), dim3(256), 0, stream>>>(qws, kws, vt2, mask, aoutb, attw);

  k_gemm_out<<<dim3(8, 32), dim3(256), 0, stream>>>(aoutb, Wbf + 3145728, bo, out0);
}